// Round 1
// 6357.227 us; speedup vs baseline: 1.2762x; 1.2762x over previous
//
#include <hip/hip_runtime.h>
#include <math.h>

#define D_MODEL 1024
#define D_INNER 2048
#define D_STATE 16
#define DT_RANK 64
#define D_CONV  4
#define N_LAYER 4
#define VOCAB   32000
#define EPS     1e-5f
#define BSZ     2
#define LSEQ    1024
#define NTOK    (BSZ*LSEQ)      // 2048 token rows

#define LOG2E   1.4426950408889634f

typedef __bf16 bf16x8 __attribute__((ext_vector_type(8)));
typedef float  f32x4  __attribute__((ext_vector_type(4)));

// ---------------------------------------------------------------- embedding
__global__ void embed_k(const int* __restrict__ tokens,
                        const float* __restrict__ emb,
                        float* __restrict__ x) {
    int row = blockIdx.x;                       // 0..2047
    int t = tokens[row];
    const float4* src = (const float4*)(emb + (size_t)t * D_MODEL);
    float4* dst = (float4*)(x + (size_t)row * D_MODEL);
    dst[threadIdx.x] = src[threadIdx.x];        // 256 thr * 4 = 1024
}

// ---------------------------------------------------------------- rmsnorm
__global__ __launch_bounds__(256) void rmsnorm_k(const float* __restrict__ x,
                                                 const float* __restrict__ w,
                                                 float* __restrict__ o) {
    int row = blockIdx.x;
    const float4* xr = (const float4*)(x + (size_t)row * D_MODEL);
    float4 v = xr[threadIdx.x];
    float ss = v.x*v.x + v.y*v.y + v.z*v.z + v.w*v.w;
    #pragma unroll
    for (int off = 32; off > 0; off >>= 1) ss += __shfl_down(ss, off, 64);
    __shared__ float sred[4];
    int wid = threadIdx.x >> 6, lane = threadIdx.x & 63;
    if (lane == 0) sred[wid] = ss;
    __syncthreads();
    float tot = sred[0] + sred[1] + sred[2] + sred[3];
    float scale = rsqrtf(tot * (1.0f / D_MODEL) + EPS);
    float4 wv = ((const float4*)w)[threadIdx.x];
    float4 ov;
    ov.x = v.x * scale * wv.x;
    ov.y = v.y * scale * wv.y;
    ov.z = v.z * scale * wv.z;
    ov.w = v.w * scale * wv.w;
    ((float4*)(o + (size_t)row * D_MODEL))[threadIdx.x] = ov;
}

// ---------------------------------------------------------------- fp32 GEMM
// C[M,N] = A[M,K(lda)] @ B[K,N]   (row-major)
// MODE 0: plain    MODE 1: +bias[col], softplus    MODE 2: +aux[row,col] (residual)
// 64x64 tile, 256 threads, 4x4 per-thread micro-tile, K-tile 16.
template<int MODE>
__global__ __launch_bounds__(256) void gemm_k(const float* __restrict__ A,
                                              const float* __restrict__ B,
                                              float* __restrict__ C,
                                              int M, int N, int K, int lda,
                                              const float* __restrict__ aux) {
    __shared__ float As[16][68];   // [k][m], row stride 68 floats = 17*16B (f4-aligned)
    __shared__ float Bs[16][68];   // [k][n]
    int tid = threadIdx.x;
    int tx = tid & 15, ty = tid >> 4;
    int rowBase = blockIdx.y * 64;
    int colBase = blockIdx.x * 64;
    float acc[4][4] = {};

    for (int k0 = 0; k0 < K; k0 += 16) {
        #pragma unroll
        for (int i = 0; i < 4; i++) {           // A tile: 64 rows x 16 k
            int lin = tid + i * 256;
            int r = lin >> 4, kk = lin & 15;
            As[kk][r] = A[(size_t)(rowBase + r) * lda + k0 + kk];
        }
        #pragma unroll
        for (int i = 0; i < 4; i++) {           // B tile: 16 k x 64 cols
            int lin = tid + i * 256;
            int kk = lin >> 6, c = lin & 63;
            int col = colBase + c;
            Bs[kk][c] = (col < N) ? B[(size_t)(k0 + kk) * N + col] : 0.f;
        }
        __syncthreads();
        #pragma unroll
        for (int kk = 0; kk < 16; kk++) {
            float4 a4 = *(const float4*)&As[kk][ty * 4];
            float4 b4 = *(const float4*)&Bs[kk][tx * 4];
            float av[4] = {a4.x, a4.y, a4.z, a4.w};
            float bv[4] = {b4.x, b4.y, b4.z, b4.w};
            #pragma unroll
            for (int i = 0; i < 4; i++)
                #pragma unroll
                for (int j = 0; j < 4; j++)
                    acc[i][j] = fmaf(av[i], bv[j], acc[i][j]);
        }
        __syncthreads();
    }

    int col = colBase + tx * 4;                 // N % 4 == 0 for all our calls
    if (col < N) {
        #pragma unroll
        for (int i = 0; i < 4; i++) {
            int row = rowBase + ty * 4 + i;
            float v0 = acc[i][0], v1 = acc[i][1], v2 = acc[i][2], v3 = acc[i][3];
            if (MODE == 1) {
                const float4 bb = *(const float4*)&aux[col];
                v0 += bb.x; v1 += bb.y; v2 += bb.z; v3 += bb.w;
                v0 = (v0 > 20.f) ? v0 : log1pf(__expf(v0));
                v1 = (v1 > 20.f) ? v1 : log1pf(__expf(v1));
                v2 = (v2 > 20.f) ? v2 : log1pf(__expf(v2));
                v3 = (v3 > 20.f) ? v3 : log1pf(__expf(v3));
            } else if (MODE == 2) {
                const float4 rr = *(const float4*)&aux[(size_t)row * N + col];
                v0 += rr.x; v1 += rr.y; v2 += rr.z; v3 += rr.w;
            }
            float4 ov; ov.x = v0; ov.y = v1; ov.z = v2; ov.w = v3;
            *(float4*)&C[(size_t)row * N + col] = ov;
        }
    }
}

// ---------------------------------------------------------------- bf16 MFMA GEMM
// C[M,N] = A[M,K(lda)] @ B[K,N], fp32 in/out, bf16 inputs to the matrix pipe,
// fp32 accumulation. Requires M%128==0, N%128==0, K%64==0.
// 128x128 tile, BK=64, 256 threads = 4 waves (2x2), wave tile 64x64 = 4x4
// frags of v_mfma_f32_16x16x32_bf16.
// LDS: A stored [m][k] (128B rows, k-contiguous), B stored transposed [n][k].
// Both XOR-swizzled: byte ^= (row&7)<<4  (G4: raw 128B-stride = 16-way conflict).
__global__ __launch_bounds__(256) void gemm_bf16_k(const float* __restrict__ A,
                                                   const float* __restrict__ B,
                                                   float* __restrict__ C,
                                                   int M, int N, int K, int lda) {
    __shared__ __align__(16) char sA[128 * 128];   // 128 rows x 64 bf16
    __shared__ __align__(16) char sB[128 * 128];   // 128 cols x 64 bf16 (B^T)
    int tid  = threadIdx.x;
    int lane = tid & 63;
    int w    = tid >> 6;
    int wr   = w >> 1, wc = w & 1;                 // wave 2x2 grid
    int rowBase = blockIdx.y * 128;
    int n0      = blockIdx.x * 128;

    // staging assignments
    int ar  = tid >> 1;                            // A: row 0..127
    int akh = (tid & 1) * 32;                      // A: k-half (elements)
    int bn  = tid & 127;                           // B: col 0..127
    int bkh = (tid >> 7) * 32;                     // B: k-half

    f32x4 acc[4][4] = {};

    const float* Abase = A + (size_t)(rowBase + ar) * lda + akh;
    const float* Bbase = B + (size_t)bkh * N + n0 + bn;

    for (int k0 = 0; k0 < K; k0 += 64) {
        // global loads issued before the barrier (overlap with previous compute)
        f32x4 aval[8];                             // 32 contiguous floats of one A row-half
        #pragma unroll
        for (int i = 0; i < 8; i++)
            aval[i] = *(const f32x4*)(Abase + k0 + i * 4);
        float bval[32];                            // 32 k's of one B column (lane-coalesced over n)
        #pragma unroll
        for (int j = 0; j < 32; j++)
            bval[j] = Bbase[(size_t)(k0 + j) * N];

        __syncthreads();                           // previous tile's LDS reads done

        #pragma unroll
        for (int j = 0; j < 4; j++) {              // A: 32 floats -> 4x bf16x8
            bf16x8 p;
            #pragma unroll
            for (int e = 0; e < 4; e++) {
                p[e]     = (__bf16)aval[2 * j][e];
                p[4 + e] = (__bf16)aval[2 * j + 1][e];
            }
            int off = (ar * 128 + akh * 2 + j * 16) ^ ((ar & 7) << 4);
            *(bf16x8*)(sA + off) = p;
        }
        #pragma unroll
        for (int j = 0; j < 4; j++) {              // B^T: 32 floats -> 4x bf16x8
            bf16x8 p;
            #pragma unroll
            for (int e = 0; e < 8; e++) p[e] = (__bf16)bval[8 * j + e];
            int off = (bn * 128 + bkh * 2 + j * 16) ^ ((bn & 7) << 4);
            *(bf16x8*)(sB + off) = p;
        }
        __syncthreads();

        #pragma unroll
        for (int ks = 0; ks < 2; ks++) {           // two K=32 slices
            int kb = ks * 64 + (lane >> 4) * 16;   // byte offset of this lane's 8 k's
            bf16x8 af[4], bfr[4];
            #pragma unroll
            for (int mi = 0; mi < 4; mi++) {
                int m = wr * 64 + mi * 16 + (lane & 15);
                af[mi] = *(const bf16x8*)(sA + ((m * 128 + kb) ^ ((m & 7) << 4)));
            }
            #pragma unroll
            for (int ni = 0; ni < 4; ni++) {
                int n = wc * 64 + ni * 16 + (lane & 15);
                bfr[ni] = *(const bf16x8*)(sB + ((n * 128 + kb) ^ ((n & 7) << 4)));
            }
            #pragma unroll
            for (int mi = 0; mi < 4; mi++)
                #pragma unroll
                for (int ni = 0; ni < 4; ni++)
                    acc[mi][ni] = __builtin_amdgcn_mfma_f32_16x16x32_bf16(
                        af[mi], bfr[ni], acc[mi][ni], 0, 0, 0);
        }
    }

    // epilogue: C/D layout col=lane&15, row=(lane>>4)*4+reg
    #pragma unroll
    for (int mi = 0; mi < 4; mi++) {
        int row = rowBase + wr * 64 + mi * 16 + (lane >> 4) * 4;
        #pragma unroll
        for (int ni = 0; ni < 4; ni++) {
            int col = n0 + wc * 64 + ni * 16 + (lane & 15);
            #pragma unroll
            for (int r = 0; r < 4; r++)
                C[(size_t)(row + r) * N + col] = acc[mi][ni][r];
        }
    }
}

// ---------------------------------------------------------------- conv1d + silu
// u[t,d] = silu( cb[d] + sum_k cw[d,k] * xz[t-3+k, d] )   (u-half of xz, causal in l)
__global__ __launch_bounds__(256) void conv_silu_k(const float* __restrict__ xz,
                                                   const float* __restrict__ cw,
                                                   const float* __restrict__ cb,
                                                   float* __restrict__ u) {
    int d = blockIdx.x * 256 + threadIdx.x;     // 0..2047
    int t = blockIdx.y;                          // b*L + l
    int l = t & (LSEQ - 1);
    float acc = cb[d];
    #pragma unroll
    for (int k = 0; k < D_CONV; k++) {
        int ll = l - (D_CONV - 1) + k;
        if (ll >= 0)
            acc = fmaf(cw[d * D_CONV + k], xz[(size_t)(t - (D_CONV - 1) + k) * (2 * D_INNER) + d], acc);
    }
    float s = acc / (1.f + __expf(-acc));        // silu
    u[(size_t)t * D_INNER + d] = s;
}

// ---------------------------------------------------------------- selective scan
// thread owns (b, d); h[16] in registers; B/C staged in LDS per 32-l chunk.
__global__ __launch_bounds__(256) void scan_k(const float* __restrict__ u,
                                              const float* __restrict__ dt,
                                              const float* __restrict__ dbl,
                                              const float* __restrict__ A_log,
                                              const float* __restrict__ Dp,
                                              float* __restrict__ y) {
    int b = blockIdx.x >> 3;                     // 8 blocks per batch
    int d = (blockIdx.x & 7) * 256 + threadIdx.x;
    float A2[D_STATE];
    #pragma unroll
    for (int n = 0; n < D_STATE; n++)
        A2[n] = -__expf(A_log[(size_t)d * D_STATE + n]) * LOG2E;   // A * log2(e)
    float Dd = Dp[d];
    float h[D_STATE];
    #pragma unroll
    for (int n = 0; n < D_STATE; n++) h[n] = 0.f;

    __shared__ float bc[32][32];                 // [l-chunk][B(16)|C(16)]
    for (int c0 = 0; c0 < LSEQ; c0 += 32) {
        __syncthreads();
        #pragma unroll
        for (int i = 0; i < 4; i++) {
            int lin = threadIdx.x + i * 256;
            int li = lin >> 5, j = lin & 31;
            bc[li][j] = dbl[(size_t)(b * LSEQ + c0 + li) * 96 + 64 + j];
        }
        __syncthreads();
        for (int li = 0; li < 32; li++) {
            int t = b * LSEQ + c0 + li;
            float dtv = dt[(size_t)t * D_INNER + d];
            float uv  = u[(size_t)t * D_INNER + d];
            float dbu = dtv * uv;
            float yv = 0.f;
            #pragma unroll
            for (int n = 0; n < D_STATE; n++) {
                float dA = exp2f(dtv * A2[n]);
                h[n] = fmaf(dA, h[n], dbu * bc[li][n]);
                yv = fmaf(h[n], bc[li][16 + n], yv);
            }
            y[(size_t)t * D_INNER + d] = yv + uv * Dd;
        }
    }
}

// ---------------------------------------------------------------- gate: y *= silu(z)
__global__ __launch_bounds__(256) void gate_k(const float* __restrict__ xz,
                                              float* __restrict__ y) {
    size_t i = (size_t)blockIdx.x * 256 + threadIdx.x;   // over NTOK*D_INNER
    size_t t = i >> 11;                                   // / D_INNER
    int d = (int)(i & (D_INNER - 1));
    float z = xz[t * (2 * D_INNER) + D_INNER + d];
    y[i] *= z / (1.f + __expf(-z));
}

// ---------------------------------------------------------------- launch
extern "C" void kernel_launch(void* const* d_in, const int* in_sizes, int n_in,
                              void* d_out, int out_size, void* d_ws, size_t ws_size,
                              hipStream_t stream) {
    const int*   tokens   = (const int*)  d_in[0];
    const float* emb      = (const float*)d_in[1];
    const float* norm_w   = (const float*)d_in[2];
    const float* in_proj  = (const float*)d_in[3];
    const float* conv_w   = (const float*)d_in[4];
    const float* conv_b   = (const float*)d_in[5];
    const float* x_proj   = (const float*)d_in[6];
    const float* dt_w     = (const float*)d_in[7];
    const float* dt_b     = (const float*)d_in[8];
    const float* A_log    = (const float*)d_in[9];
    const float* Dp       = (const float*)d_in[10];
    const float* out_proj = (const float*)d_in[11];
    const float* fin_w    = (const float*)d_in[12];
    const float* head_w   = (const float*)d_in[13];
    float* out = (float*)d_out;

    // small persistent scratch in d_ws (~17.6 MB)
    float* ws  = (float*)d_ws;
    float* x   = ws;                       // 2,097,152
    float* xn  = ws + 2097152;             // 2,097,152
    float* dbl = ws + 4194304;             //   196,608

    // big transient scratch inside d_out (overwritten by head GEMM at the end)
    float* xz = out;                       // 8,388,608  [2048 x 4096]
    float* u  = out + 8388608;             // 4,194,304  [2048 x 2048]
    float* dt = out + 12582912;            // 4,194,304
    float* y  = out + 16777216;            // 4,194,304

    embed_k<<<NTOK, 256, 0, stream>>>(tokens, emb, x);

    for (int i = 0; i < N_LAYER; i++) {
        rmsnorm_k<<<NTOK, 256, 0, stream>>>(x, norm_w + (size_t)i * D_MODEL, xn);
        gemm_k<0><<<dim3(64, 32), 256, 0, stream>>>(
            xn, in_proj + (size_t)i * D_MODEL * 2 * D_INNER, xz,
            NTOK, 2 * D_INNER, D_MODEL, D_MODEL, nullptr);
        conv_silu_k<<<dim3(8, NTOK), 256, 0, stream>>>(
            xz, conv_w + (size_t)i * D_INNER * D_CONV, conv_b + (size_t)i * D_INNER, u);
        gemm_k<0><<<dim3(2, 32), 256, 0, stream>>>(
            u, x_proj + (size_t)i * D_INNER * 96, dbl,
            NTOK, 96, D_INNER, D_INNER, nullptr);
        gemm_k<1><<<dim3(32, 32), 256, 0, stream>>>(
            dbl, dt_w + (size_t)i * DT_RANK * D_INNER, dt,
            NTOK, D_INNER, DT_RANK, 96, dt_b + (size_t)i * D_INNER);
        scan_k<<<16, 256, 0, stream>>>(
            u, dt, dbl, A_log + (size_t)i * D_INNER * D_STATE, Dp + (size_t)i * D_INNER, y);
        gate_k<<<(NTOK * D_INNER) / 256, 256, 0, stream>>>(xz, y);
        gemm_k<2><<<dim3(16, 32), 256, 0, stream>>>(
            y, out_proj + (size_t)i * D_INNER * D_MODEL, x,
            NTOK, D_MODEL, D_INNER, D_INNER, x);
    }

    rmsnorm_k<<<NTOK, 256, 0, stream>>>(x, fin_w, xn);
    // head GEMM: 2048 x 32000 x 1024 — bf16 MFMA (was the #1 dispatch at ~1980 us)
    gemm_bf16_k<<<dim3(VOCAB / 128, NTOK / 128), 256, 0, stream>>>(
        xn, head_w, out, NTOK, VOCAB, D_MODEL, D_MODEL);
}

// Round 2
// 4049.664 us; speedup vs baseline: 2.0035x; 1.5698x over previous
//
#include <hip/hip_runtime.h>
#include <math.h>

#define D_MODEL 1024
#define D_INNER 2048
#define D_STATE 16
#define DT_RANK 64
#define D_CONV  4
#define N_LAYER 4
#define VOCAB   32000
#define EPS     1e-5f
#define BSZ     2
#define LSEQ    1024
#define NTOK    (BSZ*LSEQ)      // 2048 token rows

#define LOG2E   1.4426950408889634f

// chunked selective-scan decomposition
#define NCHUNK  32
#define CLEN    (LSEQ / NCHUNK)   // 32

typedef __bf16 bf16x8 __attribute__((ext_vector_type(8)));
typedef float  f32x4  __attribute__((ext_vector_type(4)));

// ---------------------------------------------------------------- embedding
__global__ void embed_k(const int* __restrict__ tokens,
                        const float* __restrict__ emb,
                        float* __restrict__ x) {
    int row = blockIdx.x;                       // 0..2047
    int t = tokens[row];
    const float4* src = (const float4*)(emb + (size_t)t * D_MODEL);
    float4* dst = (float4*)(x + (size_t)row * D_MODEL);
    dst[threadIdx.x] = src[threadIdx.x];        // 256 thr * 4 = 1024
}

// ---------------------------------------------------------------- rmsnorm
__global__ __launch_bounds__(256) void rmsnorm_k(const float* __restrict__ x,
                                                 const float* __restrict__ w,
                                                 float* __restrict__ o) {
    int row = blockIdx.x;
    const float4* xr = (const float4*)(x + (size_t)row * D_MODEL);
    float4 v = xr[threadIdx.x];
    float ss = v.x*v.x + v.y*v.y + v.z*v.z + v.w*v.w;
    #pragma unroll
    for (int off = 32; off > 0; off >>= 1) ss += __shfl_down(ss, off, 64);
    __shared__ float sred[4];
    int wid = threadIdx.x >> 6, lane = threadIdx.x & 63;
    if (lane == 0) sred[wid] = ss;
    __syncthreads();
    float tot = sred[0] + sred[1] + sred[2] + sred[3];
    float scale = rsqrtf(tot * (1.0f / D_MODEL) + EPS);
    float4 wv = ((const float4*)w)[threadIdx.x];
    float4 ov;
    ov.x = v.x * scale * wv.x;
    ov.y = v.y * scale * wv.y;
    ov.z = v.z * scale * wv.z;
    ov.w = v.w * scale * wv.w;
    ((float4*)(o + (size_t)row * D_MODEL))[threadIdx.x] = ov;
}

// ---------------------------------------------------------------- fp32 GEMM
// C[M,N] = A[M,K(lda)] @ B[K,N]   (row-major)
// MODE 0: plain    MODE 1: +bias[col], softplus    MODE 2: +aux[row,col] (residual)
// 64x64 tile, 256 threads, 4x4 per-thread micro-tile, K-tile 16.
template<int MODE>
__global__ __launch_bounds__(256) void gemm_k(const float* __restrict__ A,
                                              const float* __restrict__ B,
                                              float* __restrict__ C,
                                              int M, int N, int K, int lda,
                                              const float* __restrict__ aux) {
    __shared__ float As[16][68];   // [k][m], row stride 68 floats = 17*16B (f4-aligned)
    __shared__ float Bs[16][68];   // [k][n]
    int tid = threadIdx.x;
    int tx = tid & 15, ty = tid >> 4;
    int rowBase = blockIdx.y * 64;
    int colBase = blockIdx.x * 64;
    float acc[4][4] = {};

    for (int k0 = 0; k0 < K; k0 += 16) {
        #pragma unroll
        for (int i = 0; i < 4; i++) {           // A tile: 64 rows x 16 k
            int lin = tid + i * 256;
            int r = lin >> 4, kk = lin & 15;
            As[kk][r] = A[(size_t)(rowBase + r) * lda + k0 + kk];
        }
        #pragma unroll
        for (int i = 0; i < 4; i++) {           // B tile: 16 k x 64 cols
            int lin = tid + i * 256;
            int kk = lin >> 6, c = lin & 63;
            int col = colBase + c;
            Bs[kk][c] = (col < N) ? B[(size_t)(k0 + kk) * N + col] : 0.f;
        }
        __syncthreads();
        #pragma unroll
        for (int kk = 0; kk < 16; kk++) {
            float4 a4 = *(const float4*)&As[kk][ty * 4];
            float4 b4 = *(const float4*)&Bs[kk][tx * 4];
            float av[4] = {a4.x, a4.y, a4.z, a4.w};
            float bv[4] = {b4.x, b4.y, b4.z, b4.w};
            #pragma unroll
            for (int i = 0; i < 4; i++)
                #pragma unroll
                for (int j = 0; j < 4; j++)
                    acc[i][j] = fmaf(av[i], bv[j], acc[i][j]);
        }
        __syncthreads();
    }

    int col = colBase + tx * 4;                 // N % 4 == 0 for all our calls
    if (col < N) {
        #pragma unroll
        for (int i = 0; i < 4; i++) {
            int row = rowBase + ty * 4 + i;
            float v0 = acc[i][0], v1 = acc[i][1], v2 = acc[i][2], v3 = acc[i][3];
            if (MODE == 1) {
                const float4 bb = *(const float4*)&aux[col];
                v0 += bb.x; v1 += bb.y; v2 += bb.z; v3 += bb.w;
                v0 = (v0 > 20.f) ? v0 : log1pf(__expf(v0));
                v1 = (v1 > 20.f) ? v1 : log1pf(__expf(v1));
                v2 = (v2 > 20.f) ? v2 : log1pf(__expf(v2));
                v3 = (v3 > 20.f) ? v3 : log1pf(__expf(v3));
            } else if (MODE == 2) {
                const float4 rr = *(const float4*)&aux[(size_t)row * N + col];
                v0 += rr.x; v1 += rr.y; v2 += rr.z; v3 += rr.w;
            }
            float4 ov; ov.x = v0; ov.y = v1; ov.z = v2; ov.w = v3;
            *(float4*)&C[(size_t)row * N + col] = ov;
        }
    }
}

// ---------------------------------------------------------------- bf16 MFMA GEMM
// C[M,N] = A[M,K(lda)] @ B[K,N], fp32 in/out, bf16 inputs to the matrix pipe,
// fp32 accumulation. Requires M%128==0, N%128==0, K%64==0.
__global__ __launch_bounds__(256) void gemm_bf16_k(const float* __restrict__ A,
                                                   const float* __restrict__ B,
                                                   float* __restrict__ C,
                                                   int M, int N, int K, int lda) {
    __shared__ __align__(16) char sA[128 * 128];   // 128 rows x 64 bf16
    __shared__ __align__(16) char sB[128 * 128];   // 128 cols x 64 bf16 (B^T)
    int tid  = threadIdx.x;
    int lane = tid & 63;
    int w    = tid >> 6;
    int wr   = w >> 1, wc = w & 1;                 // wave 2x2 grid
    int rowBase = blockIdx.y * 128;
    int n0      = blockIdx.x * 128;

    // staging assignments
    int ar  = tid >> 1;                            // A: row 0..127
    int akh = (tid & 1) * 32;                      // A: k-half (elements)
    int bn  = tid & 127;                           // B: col 0..127
    int bkh = (tid >> 7) * 32;                     // B: k-half

    f32x4 acc[4][4] = {};

    const float* Abase = A + (size_t)(rowBase + ar) * lda + akh;
    const float* Bbase = B + (size_t)bkh * N + n0 + bn;

    for (int k0 = 0; k0 < K; k0 += 64) {
        // global loads issued before the barrier (overlap with previous compute)
        f32x4 aval[8];                             // 32 contiguous floats of one A row-half
        #pragma unroll
        for (int i = 0; i < 8; i++)
            aval[i] = *(const f32x4*)(Abase + k0 + i * 4);
        float bval[32];                            // 32 k's of one B column (lane-coalesced over n)
        #pragma unroll
        for (int j = 0; j < 32; j++)
            bval[j] = Bbase[(size_t)(k0 + j) * N];

        __syncthreads();                           // previous tile's LDS reads done

        #pragma unroll
        for (int j = 0; j < 4; j++) {              // A: 32 floats -> 4x bf16x8
            bf16x8 p;
            #pragma unroll
            for (int e = 0; e < 4; e++) {
                p[e]     = (__bf16)aval[2 * j][e];
                p[4 + e] = (__bf16)aval[2 * j + 1][e];
            }
            int off = (ar * 128 + akh * 2 + j * 16) ^ ((ar & 7) << 4);
            *(bf16x8*)(sA + off) = p;
        }
        #pragma unroll
        for (int j = 0; j < 4; j++) {              // B^T: 32 floats -> 4x bf16x8
            bf16x8 p;
            #pragma unroll
            for (int e = 0; e < 8; e++) p[e] = (__bf16)bval[8 * j + e];
            int off = (bn * 128 + bkh * 2 + j * 16) ^ ((bn & 7) << 4);
            *(bf16x8*)(sB + off) = p;
        }
        __syncthreads();

        #pragma unroll
        for (int ks = 0; ks < 2; ks++) {           // two K=32 slices
            int kb = ks * 64 + (lane >> 4) * 16;   // byte offset of this lane's 8 k's
            bf16x8 af[4], bfr[4];
            #pragma unroll
            for (int mi = 0; mi < 4; mi++) {
                int m = wr * 64 + mi * 16 + (lane & 15);
                af[mi] = *(const bf16x8*)(sA + ((m * 128 + kb) ^ ((m & 7) << 4)));
            }
            #pragma unroll
            for (int ni = 0; ni < 4; ni++) {
                int n = wc * 64 + ni * 16 + (lane & 15);
                bfr[ni] = *(const bf16x8*)(sB + ((n * 128 + kb) ^ ((n & 7) << 4)));
            }
            #pragma unroll
            for (int mi = 0; mi < 4; mi++)
                #pragma unroll
                for (int ni = 0; ni < 4; ni++)
                    acc[mi][ni] = __builtin_amdgcn_mfma_f32_16x16x32_bf16(
                        af[mi], bfr[ni], acc[mi][ni], 0, 0, 0);
        }
    }

    // epilogue: C/D layout col=lane&15, row=(lane>>4)*4+reg
    #pragma unroll
    for (int mi = 0; mi < 4; mi++) {
        int row = rowBase + wr * 64 + mi * 16 + (lane >> 4) * 4;
        #pragma unroll
        for (int ni = 0; ni < 4; ni++) {
            int col = n0 + wc * 64 + ni * 16 + (lane & 15);
            #pragma unroll
            for (int r = 0; r < 4; r++)
                C[(size_t)(row + r) * N + col] = acc[mi][ni][r];
        }
    }
}

// ---------------------------------------------------------------- conv1d + silu
__global__ __launch_bounds__(256) void conv_silu_k(const float* __restrict__ xz,
                                                   const float* __restrict__ cw,
                                                   const float* __restrict__ cb,
                                                   float* __restrict__ u) {
    int d = blockIdx.x * 256 + threadIdx.x;     // 0..2047
    int t = blockIdx.y;                          // b*L + l
    int l = t & (LSEQ - 1);
    float acc = cb[d];
    #pragma unroll
    for (int k = 0; k < D_CONV; k++) {
        int ll = l - (D_CONV - 1) + k;
        if (ll >= 0)
            acc = fmaf(cw[d * D_CONV + k], xz[(size_t)(t - (D_CONV - 1) + k) * (2 * D_INNER) + d], acc);
    }
    float s = acc / (1.f + __expf(-acc));        // silu
    u[(size_t)t * D_INNER + d] = s;
}

// ---------------------------------------------------------------- chunked selective scan
// Linear recurrence h_t = dA_t*h_{t-1} + dBu_t decomposed over NCHUNK chunks:
//   h_end(chunk) = P*h_in + h_local,  P = prod(dA),  h_local = zero-init scan.
// pass1: per (b,chunk,d) compute h_local[16], P[16].          grid 2*32*8=512 blk
// combine: per (b,d,n) chain h_in over chunks (coalesced).    grid 256 blk
// pass2: replay chunk with true h_in, emit y.                 grid 512 blk

__global__ __launch_bounds__(256) void scan_pass1_k(const float* __restrict__ u,
                                                    const float* __restrict__ dt,
                                                    const float* __restrict__ dbl,
                                                    const float* __restrict__ A_log,
                                                    float* __restrict__ hloc,
                                                    float* __restrict__ Pc) {
    int d = blockIdx.x * 256 + threadIdx.x;      // 0..2047
    int c = blockIdx.y;                          // chunk
    int b = blockIdx.z;
    float A2[D_STATE];
    #pragma unroll
    for (int n = 0; n < D_STATE; n++)
        A2[n] = -__expf(A_log[(size_t)d * D_STATE + n]) * LOG2E;   // A * log2(e)

    float h[D_STATE], P[D_STATE];
    #pragma unroll
    for (int n = 0; n < D_STATE; n++) { h[n] = 0.f; P[n] = 1.f; }

    __shared__ float bs[CLEN][D_STATE];          // 32 x 16 B-values
    #pragma unroll
    for (int i = 0; i < 2; i++) {
        int lin = threadIdx.x + i * 256;
        int li = lin >> 4, j = lin & 15;
        bs[li][j] = dbl[(size_t)(b * LSEQ + c * CLEN + li) * 96 + 64 + j];
    }
    __syncthreads();

    int t0 = b * LSEQ + c * CLEN;
    for (int li = 0; li < CLEN; li++) {
        float dtv = dt[(size_t)(t0 + li) * D_INNER + d];
        float uv  = u[(size_t)(t0 + li) * D_INNER + d];
        float dbu = dtv * uv;
        #pragma unroll
        for (int n = 0; n < D_STATE; n++) {
            float dA = exp2f(dtv * A2[n]);
            h[n] = fmaf(dA, h[n], dbu * bs[li][n]);
            P[n] *= dA;
        }
    }
    size_t o = ((size_t)(b * NCHUNK + c) * D_INNER + d) * D_STATE;
    #pragma unroll
    for (int n = 0; n < D_STATE; n += 4) {
        float4 hv = make_float4(h[n], h[n+1], h[n+2], h[n+3]);
        float4 pv = make_float4(P[n], P[n+1], P[n+2], P[n+3]);
        *(float4*)&hloc[o + n] = hv;
        *(float4*)&Pc[o + n]   = pv;
    }
}

__global__ __launch_bounds__(256) void scan_combine_k(const float* __restrict__ hloc,
                                                      const float* __restrict__ Pc,
                                                      float* __restrict__ hin) {
    int gi = blockIdx.x * 256 + threadIdx.x;     // over B*D_INNER*D_STATE = 65536
    int n = gi & 15;
    int d = (gi >> 4) & (D_INNER - 1);
    int b = gi >> 15;
    float h = 0.f;
    #pragma unroll
    for (int c = 0; c < NCHUNK; c++) {
        size_t o = ((size_t)(b * NCHUNK + c) * D_INNER + d) * D_STATE + n;
        hin[o] = h;
        h = fmaf(Pc[o], h, hloc[o]);
    }
}

__global__ __launch_bounds__(256) void scan_pass2_k(const float* __restrict__ u,
                                                    const float* __restrict__ dt,
                                                    const float* __restrict__ dbl,
                                                    const float* __restrict__ A_log,
                                                    const float* __restrict__ Dp,
                                                    const float* __restrict__ hin,
                                                    float* __restrict__ y) {
    int d = blockIdx.x * 256 + threadIdx.x;
    int c = blockIdx.y;
    int b = blockIdx.z;
    float A2[D_STATE];
    #pragma unroll
    for (int n = 0; n < D_STATE; n++)
        A2[n] = -__expf(A_log[(size_t)d * D_STATE + n]) * LOG2E;
    float Dd = Dp[d];

    float h[D_STATE];
    {
        size_t o = ((size_t)(b * NCHUNK + c) * D_INNER + d) * D_STATE;
        #pragma unroll
        for (int n = 0; n < D_STATE; n += 4) {
            float4 hv = *(const float4*)&hin[o + n];
            h[n] = hv.x; h[n+1] = hv.y; h[n+2] = hv.z; h[n+3] = hv.w;
        }
    }

    __shared__ float bc[CLEN][32];               // 32 x [B(16)|C(16)]
    #pragma unroll
    for (int i = 0; i < 4; i++) {
        int lin = threadIdx.x + i * 256;
        int li = lin >> 5, j = lin & 31;
        bc[li][j] = dbl[(size_t)(b * LSEQ + c * CLEN + li) * 96 + 64 + j];
    }
    __syncthreads();

    int t0 = b * LSEQ + c * CLEN;
    for (int li = 0; li < CLEN; li++) {
        int t = t0 + li;
        float dtv = dt[(size_t)t * D_INNER + d];
        float uv  = u[(size_t)t * D_INNER + d];
        float dbu = dtv * uv;
        float yv = 0.f;
        #pragma unroll
        for (int n = 0; n < D_STATE; n++) {
            float dA = exp2f(dtv * A2[n]);
            h[n] = fmaf(dA, h[n], dbu * bc[li][n]);
            yv = fmaf(h[n], bc[li][16 + n], yv);
        }
        y[(size_t)t * D_INNER + d] = yv + uv * Dd;
    }
}

// ---------------------------------------------------------------- gate: y *= silu(z)
__global__ __launch_bounds__(256) void gate_k(const float* __restrict__ xz,
                                              float* __restrict__ y) {
    size_t i = (size_t)blockIdx.x * 256 + threadIdx.x;   // over NTOK*D_INNER
    size_t t = i >> 11;                                   // / D_INNER
    int d = (int)(i & (D_INNER - 1));
    float z = xz[t * (2 * D_INNER) + D_INNER + d];
    y[i] *= z / (1.f + __expf(-z));
}

// ---------------------------------------------------------------- launch
extern "C" void kernel_launch(void* const* d_in, const int* in_sizes, int n_in,
                              void* d_out, int out_size, void* d_ws, size_t ws_size,
                              hipStream_t stream) {
    const int*   tokens   = (const int*)  d_in[0];
    const float* emb      = (const float*)d_in[1];
    const float* norm_w   = (const float*)d_in[2];
    const float* in_proj  = (const float*)d_in[3];
    const float* conv_w   = (const float*)d_in[4];
    const float* conv_b   = (const float*)d_in[5];
    const float* x_proj   = (const float*)d_in[6];
    const float* dt_w     = (const float*)d_in[7];
    const float* dt_b     = (const float*)d_in[8];
    const float* A_log    = (const float*)d_in[9];
    const float* Dp       = (const float*)d_in[10];
    const float* out_proj = (const float*)d_in[11];
    const float* fin_w    = (const float*)d_in[12];
    const float* head_w   = (const float*)d_in[13];
    float* out = (float*)d_out;

    // small persistent scratch in d_ws (~17.6 MB)
    float* ws  = (float*)d_ws;
    float* x   = ws;                       // 2,097,152
    float* xn  = ws + 2097152;             // 2,097,152
    float* dbl = ws + 4194304;             //   196,608

    // big transient scratch inside d_out (overwritten by head GEMM at the end)
    // out region = 2048*32000 = 65,536,000 floats total
    float* xz   = out;                     // 8,388,608  [2048 x 4096]
    float* u    = out + 8388608;           // 4,194,304  [2048 x 2048]
    float* dt   = out + 12582912;          // 4,194,304
    float* y    = out + 16777216;          // 4,194,304
    float* hloc = out + 20971520;          // 2,097,152  [B*NCHUNK*D_INNER*16]
    float* Pc   = out + 23068672;          // 2,097,152
    float* hin  = out + 25165824;          // 2,097,152

    embed_k<<<NTOK, 256, 0, stream>>>(tokens, emb, x);

    for (int i = 0; i < N_LAYER; i++) {
        rmsnorm_k<<<NTOK, 256, 0, stream>>>(x, norm_w + (size_t)i * D_MODEL, xn);
        gemm_k<0><<<dim3(64, 32), 256, 0, stream>>>(
            xn, in_proj + (size_t)i * D_MODEL * 2 * D_INNER, xz,
            NTOK, 2 * D_INNER, D_MODEL, D_MODEL, nullptr);
        conv_silu_k<<<dim3(8, NTOK), 256, 0, stream>>>(
            xz, conv_w + (size_t)i * D_INNER * D_CONV, conv_b + (size_t)i * D_INNER, u);
        gemm_k<0><<<dim3(2, 32), 256, 0, stream>>>(
            u, x_proj + (size_t)i * D_INNER * 96, dbl,
            NTOK, 96, D_INNER, D_INNER, nullptr);
        gemm_k<1><<<dim3(32, 32), 256, 0, stream>>>(
            dbl, dt_w + (size_t)i * DT_RANK * D_INNER, dt,
            NTOK, D_INNER, DT_RANK, 96, dt_b + (size_t)i * D_INNER);

        // chunked selective scan (was: scan_k at 645 us, 16 blocks)
        scan_pass1_k<<<dim3(8, NCHUNK, BSZ), 256, 0, stream>>>(
            u, dt, dbl, A_log + (size_t)i * D_INNER * D_STATE, hloc, Pc);
        scan_combine_k<<<256, 256, 0, stream>>>(hloc, Pc, hin);
        scan_pass2_k<<<dim3(8, NCHUNK, BSZ), 256, 0, stream>>>(
            u, dt, dbl, A_log + (size_t)i * D_INNER * D_STATE,
            Dp + (size_t)i * D_INNER, hin, y);

        gate_k<<<(NTOK * D_INNER) / 256, 256, 0, stream>>>(xz, y);
        gemm_k<2><<<dim3(16, 32), 256, 0, stream>>>(
            y, out_proj + (size_t)i * D_INNER * D_MODEL, x,
            NTOK, D_MODEL, D_INNER, D_INNER, x);
    }

    rmsnorm_k<<<NTOK, 256, 0, stream>>>(x, fin_w, xn);
    // head GEMM: 2048 x 32000 x 1024 — bf16 MFMA
    gemm_bf16_k<<<dim3(VOCAB / 128, NTOK / 128), 256, 0, stream>>>(
        xn, head_w, out, NTOK, VOCAB, D_MODEL, D_MODEL);
}

// Round 3
// 2341.692 us; speedup vs baseline: 3.4647x; 1.7294x over previous
//
#include <hip/hip_runtime.h>
#include <math.h>

#define D_MODEL 1024
#define D_INNER 2048
#define D_STATE 16
#define DT_RANK 64
#define D_CONV  4
#define N_LAYER 4
#define VOCAB   32000
#define EPS     1e-5f
#define BSZ     2
#define LSEQ    1024
#define NTOK    (BSZ*LSEQ)      // 2048 token rows

#define LOG2E   1.4426950408889634f

// chunked selective-scan decomposition
#define NCHUNK  32
#define CLEN    (LSEQ / NCHUNK)   // 32

typedef __bf16 bf16x8 __attribute__((ext_vector_type(8)));
typedef __bf16 bf16x4 __attribute__((ext_vector_type(4)));
typedef float  f32x4  __attribute__((ext_vector_type(4)));

// async global->LDS, 16B per lane; LDS dest is wave-uniform base + lane*16
__device__ __forceinline__ void gload16(const void* g, void* l) {
    __builtin_amdgcn_global_load_lds(
        (const __attribute__((address_space(1))) void*)g,
        (__attribute__((address_space(3))) void*)l, 16, 0, 0);
}

// ---------------------------------------------------------------- embedding
__global__ void embed_k(const int* __restrict__ tokens,
                        const float* __restrict__ emb,
                        float* __restrict__ x) {
    int row = blockIdx.x;                       // 0..2047
    int t = tokens[row];
    const float4* src = (const float4*)(emb + (size_t)t * D_MODEL);
    float4* dst = (float4*)(x + (size_t)row * D_MODEL);
    dst[threadIdx.x] = src[threadIdx.x];        // 256 thr * 4 = 1024
}

// ---------------------------------------------------------------- rmsnorm -> bf16
__global__ __launch_bounds__(256) void rmsnorm_bf_k(const float* __restrict__ x,
                                                    const float* __restrict__ w,
                                                    __bf16* __restrict__ o) {
    int row = blockIdx.x;
    const float4* xr = (const float4*)(x + (size_t)row * D_MODEL);
    float4 v = xr[threadIdx.x];
    float ss = v.x*v.x + v.y*v.y + v.z*v.z + v.w*v.w;
    #pragma unroll
    for (int off = 32; off > 0; off >>= 1) ss += __shfl_down(ss, off, 64);
    __shared__ float sred[4];
    int wid = threadIdx.x >> 6, lane = threadIdx.x & 63;
    if (lane == 0) sred[wid] = ss;
    __syncthreads();
    float tot = sred[0] + sred[1] + sred[2] + sred[3];
    float scale = rsqrtf(tot * (1.0f / D_MODEL) + EPS);
    float4 wv = ((const float4*)w)[threadIdx.x];
    bf16x4 ov;
    ov[0] = (__bf16)(v.x * scale * wv.x);
    ov[1] = (__bf16)(v.y * scale * wv.y);
    ov[2] = (__bf16)(v.z * scale * wv.z);
    ov[3] = (__bf16)(v.w * scale * wv.w);
    *(bf16x4*)(o + (size_t)row * D_MODEL + threadIdx.x * 4) = ov;
}

// ---------------------------------------------------------------- fp32 GEMM (x_proj / dt_proj)
// MODE 0: plain    MODE 1: +bias[col], softplus
template<int MODE>
__global__ __launch_bounds__(256) void gemm_k(const float* __restrict__ A,
                                              const float* __restrict__ B,
                                              float* __restrict__ C,
                                              int M, int N, int K, int lda,
                                              const float* __restrict__ aux) {
    __shared__ float As[16][68];
    __shared__ float Bs[16][68];
    int tid = threadIdx.x;
    int tx = tid & 15, ty = tid >> 4;
    int rowBase = blockIdx.y * 64;
    int colBase = blockIdx.x * 64;
    float acc[4][4] = {};

    for (int k0 = 0; k0 < K; k0 += 16) {
        #pragma unroll
        for (int i = 0; i < 4; i++) {           // A tile: 64 rows x 16 k
            int lin = tid + i * 256;
            int r = lin >> 4, kk = lin & 15;
            As[kk][r] = A[(size_t)(rowBase + r) * lda + k0 + kk];
        }
        #pragma unroll
        for (int i = 0; i < 4; i++) {           // B tile: 16 k x 64 cols
            int lin = tid + i * 256;
            int kk = lin >> 6, c = lin & 63;
            int col = colBase + c;
            Bs[kk][c] = (col < N) ? B[(size_t)(k0 + kk) * N + col] : 0.f;
        }
        __syncthreads();
        #pragma unroll
        for (int kk = 0; kk < 16; kk++) {
            float4 a4 = *(const float4*)&As[kk][ty * 4];
            float4 b4 = *(const float4*)&Bs[kk][tx * 4];
            float av[4] = {a4.x, a4.y, a4.z, a4.w};
            float bv[4] = {b4.x, b4.y, b4.z, b4.w};
            #pragma unroll
            for (int i = 0; i < 4; i++)
                #pragma unroll
                for (int j = 0; j < 4; j++)
                    acc[i][j] = fmaf(av[i], bv[j], acc[i][j]);
        }
        __syncthreads();
    }

    int col = colBase + tx * 4;
    if (col < N) {
        #pragma unroll
        for (int i = 0; i < 4; i++) {
            int row = rowBase + ty * 4 + i;
            float v0 = acc[i][0], v1 = acc[i][1], v2 = acc[i][2], v3 = acc[i][3];
            if (MODE == 1) {
                const float4 bb = *(const float4*)&aux[col];
                v0 += bb.x; v1 += bb.y; v2 += bb.z; v3 += bb.w;
                v0 = (v0 > 20.f) ? v0 : log1pf(__expf(v0));
                v1 = (v1 > 20.f) ? v1 : log1pf(__expf(v1));
                v2 = (v2 > 20.f) ? v2 : log1pf(__expf(v2));
                v3 = (v3 > 20.f) ? v3 : log1pf(__expf(v3));
            }
            float4 ov; ov.x = v0; ov.y = v1; ov.z = v2; ov.w = v3;
            *(float4*)&C[(size_t)row * N + col] = ov;
        }
    }
}

// ---------------------------------------------------------------- weight transpose+convert
// Wt[n][k] = (bf16) W[k][n]   per layer (blockIdx.z)
__global__ __launch_bounds__(256) void wconv_k(const float* __restrict__ W,
                                               __bf16* __restrict__ Wt,
                                               int K, int N) {
    W  += (size_t)blockIdx.z * K * N;
    Wt += (size_t)blockIdx.z * N * K;
    __shared__ float t[64][65];
    int n0 = blockIdx.x * 64, k0 = blockIdx.y * 64;
    #pragma unroll
    for (int i = 0; i < 16; i++) {
        int lin = threadIdx.x + i * 256;
        int r = lin >> 6, c = lin & 63;         // r = k-local, c = n-local
        t[r][c] = W[(size_t)(k0 + r) * N + n0 + c];
    }
    __syncthreads();
    #pragma unroll
    for (int i = 0; i < 16; i++) {
        int lin = threadIdx.x + i * 256;
        int nr = lin >> 6, kc = lin & 63;
        Wt[(size_t)(n0 + nr) * K + k0 + kc] = (__bf16)t[kc][nr];
    }
}

// ---------------------------------------------------------------- bf16 MFMA GEMM, pre-converted inputs
// C[M,N] = A[M,K] @ Bt[N,K]^T ; A,Bt bf16 (k-contiguous), C fp32.
// MODE 0: plain   MODE 2: + aux[row,col] residual
// 128x128 tile, BK=64, 4 waves 2x2, global_load_lds(16B) staging (m97 structure).
// Requires M%128==0, N%128==0, K%64==0.
template<int MODE>
__global__ __launch_bounds__(256) void gemm_bfw_k(const __bf16* __restrict__ A,
                                                  const __bf16* __restrict__ Bt,
                                                  float* __restrict__ C,
                                                  int M, int N, int K,
                                                  const float* __restrict__ aux) {
    __shared__ __align__(16) __bf16 sA[128 * 64];   // [row][64k] linear, 128B rows
    __shared__ __align__(16) __bf16 sB[128 * 64];   // [n][64k]
    int tid  = threadIdx.x;
    int lane = tid & 63;
    int w    = tid >> 6;
    int wr   = w >> 1, wc = w & 1;
    int rowBase = blockIdx.y * 128;
    int n0      = blockIdx.x * 128;

    // staging: wave w covers rows [w*32, w*32+32); slot i adds 8 rows
    int srow = w * 32 + (lane >> 3);
    int scol = (lane & 7) * 8;
    const __bf16* Ag = A  + (size_t)(rowBase + srow) * K + scol;
    const __bf16* Bg = Bt + (size_t)(n0      + srow) * K + scol;

    f32x4 acc[4][4] = {};

    for (int k0 = 0; k0 < K; k0 += 64) {
        #pragma unroll
        for (int i = 0; i < 4; i++) {
            gload16(Ag + (size_t)i * 8 * K + k0, sA + (w * 4 + i) * 512);
            gload16(Bg + (size_t)i * 8 * K + k0, sB + (w * 4 + i) * 512);
        }
        __syncthreads();                        // vmcnt(0) drain + all waves staged

        #pragma unroll
        for (int ks = 0; ks < 2; ks++) {
            int kb = ks * 32 + (lane >> 4) * 8; // k-elem offset of this lane's 8 k's
            bf16x8 af[4], bfr[4];
            #pragma unroll
            for (int mi = 0; mi < 4; mi++) {
                int m = wr * 64 + mi * 16 + (lane & 15);
                af[mi] = *(const bf16x8*)(sA + m * 64 + kb);
            }
            #pragma unroll
            for (int ni = 0; ni < 4; ni++) {
                int n = wc * 64 + ni * 16 + (lane & 15);
                bfr[ni] = *(const bf16x8*)(sB + n * 64 + kb);
            }
            #pragma unroll
            for (int mi = 0; mi < 4; mi++)
                #pragma unroll
                for (int ni = 0; ni < 4; ni++)
                    acc[mi][ni] = __builtin_amdgcn_mfma_f32_16x16x32_bf16(
                        af[mi], bfr[ni], acc[mi][ni], 0, 0, 0);
        }
        __syncthreads();                        // LDS consumed; safe to restage
    }

    // epilogue: C/D layout col=lane&15, row=(lane>>4)*4+reg
    #pragma unroll
    for (int mi = 0; mi < 4; mi++) {
        int row = rowBase + wr * 64 + mi * 16 + (lane >> 4) * 4;
        #pragma unroll
        for (int ni = 0; ni < 4; ni++) {
            int col = n0 + wc * 64 + ni * 16 + (lane & 15);
            #pragma unroll
            for (int r = 0; r < 4; r++) {
                float v = acc[mi][ni][r];
                if (MODE == 2) v += aux[(size_t)(row + r) * N + col];
                C[(size_t)(row + r) * N + col] = v;
            }
        }
    }
}

// ---------------------------------------------------------------- head GEMM
// A bf16 [M][K]; B fp32 [K][N] converted on the fly; C fp32.
// Launched dim3(M/128, N/128): M-block FASTEST so the 16 blocks sharing one
// 128-col B panel (524 KB) run concurrently -> B fetched from HBM ~once.
__global__ __launch_bounds__(256) void gemm_head_k(const __bf16* __restrict__ A,
                                                   const float* __restrict__ B,
                                                   float* __restrict__ C,
                                                   int M, int N, int K) {
    __shared__ __align__(16) char sA[128 * 128];   // 128 rows x 64 bf16, XOR-swizzled
    __shared__ __align__(16) char sB[128 * 128];   // 128 cols x 64 bf16 (B^T), XOR-swizzled
    int tid  = threadIdx.x;
    int lane = tid & 63;
    int w    = tid >> 6;
    int wr   = w >> 1, wc = w & 1;
    int rowBase = blockIdx.x * 128;                // m fastest
    int n0      = blockIdx.y * 128;

    int ar  = tid >> 1;                            // A: row 0..127
    int akh = (tid & 1) * 32;                      // A: k-half (elements)
    int bn  = tid & 127;                           // B: col 0..127
    int bkh = (tid >> 7) * 32;                     // B: k-half

    f32x4 acc[4][4] = {};

    const __bf16* Abase = A + (size_t)(rowBase + ar) * K + akh;
    const float*  Bbase = B + (size_t)bkh * N + n0 + bn;

    for (int k0 = 0; k0 < K; k0 += 64) {
        bf16x8 a8[4];                              // 32 bf16 of one A row-half
        #pragma unroll
        for (int i = 0; i < 4; i++)
            a8[i] = *(const bf16x8*)(Abase + k0 + i * 8);
        float bval[32];                            // 32 k's of one B column
        #pragma unroll
        for (int j = 0; j < 32; j++)
            bval[j] = Bbase[(size_t)(k0 + j) * N];

        __syncthreads();                           // previous tile's LDS reads done

        #pragma unroll
        for (int i = 0; i < 4; i++) {
            int off = (ar * 128 + akh * 2 + i * 16) ^ ((ar & 7) << 4);
            *(bf16x8*)(sA + off) = a8[i];
        }
        #pragma unroll
        for (int j = 0; j < 4; j++) {              // B^T: 32 floats -> 4x bf16x8
            bf16x8 p;
            #pragma unroll
            for (int e = 0; e < 8; e++) p[e] = (__bf16)bval[8 * j + e];
            int off = (bn * 128 + bkh * 2 + j * 16) ^ ((bn & 7) << 4);
            *(bf16x8*)(sB + off) = p;
        }
        __syncthreads();

        #pragma unroll
        for (int ks = 0; ks < 2; ks++) {
            int kb = ks * 64 + (lane >> 4) * 16;   // byte offset of this lane's 8 k's
            bf16x8 af[4], bfr[4];
            #pragma unroll
            for (int mi = 0; mi < 4; mi++) {
                int m = wr * 64 + mi * 16 + (lane & 15);
                af[mi] = *(const bf16x8*)(sA + ((m * 128 + kb) ^ ((m & 7) << 4)));
            }
            #pragma unroll
            for (int ni = 0; ni < 4; ni++) {
                int n = wc * 64 + ni * 16 + (lane & 15);
                bfr[ni] = *(const bf16x8*)(sB + ((n * 128 + kb) ^ ((n & 7) << 4)));
            }
            #pragma unroll
            for (int mi = 0; mi < 4; mi++)
                #pragma unroll
                for (int ni = 0; ni < 4; ni++)
                    acc[mi][ni] = __builtin_amdgcn_mfma_f32_16x16x32_bf16(
                        af[mi], bfr[ni], acc[mi][ni], 0, 0, 0);
        }
    }

    #pragma unroll
    for (int mi = 0; mi < 4; mi++) {
        int row = rowBase + wr * 64 + mi * 16 + (lane >> 4) * 4;
        #pragma unroll
        for (int ni = 0; ni < 4; ni++) {
            int col = n0 + wc * 64 + ni * 16 + (lane & 15);
            #pragma unroll
            for (int r = 0; r < 4; r++)
                C[(size_t)(row + r) * N + col] = acc[mi][ni][r];
        }
    }
}

// ---------------------------------------------------------------- conv1d + silu
__global__ __launch_bounds__(256) void conv_silu_k(const float* __restrict__ xz,
                                                   const float* __restrict__ cw,
                                                   const float* __restrict__ cb,
                                                   float* __restrict__ u) {
    int d = blockIdx.x * 256 + threadIdx.x;     // 0..2047
    int t = blockIdx.y;                          // b*L + l
    int l = t & (LSEQ - 1);
    float acc = cb[d];
    #pragma unroll
    for (int k = 0; k < D_CONV; k++) {
        int ll = l - (D_CONV - 1) + k;
        if (ll >= 0)
            acc = fmaf(cw[d * D_CONV + k], xz[(size_t)(t - (D_CONV - 1) + k) * (2 * D_INNER) + d], acc);
    }
    float s = acc / (1.f + __expf(-acc));        // silu
    u[(size_t)t * D_INNER + d] = s;
}

// ---------------------------------------------------------------- chunked selective scan
__global__ __launch_bounds__(256) void scan_pass1_k(const float* __restrict__ u,
                                                    const float* __restrict__ dt,
                                                    const float* __restrict__ dbl,
                                                    const float* __restrict__ A_log,
                                                    float* __restrict__ hloc,
                                                    float* __restrict__ Pc) {
    int d = blockIdx.x * 256 + threadIdx.x;      // 0..2047
    int c = blockIdx.y;                          // chunk
    int b = blockIdx.z;
    float A2[D_STATE];
    #pragma unroll
    for (int n = 0; n < D_STATE; n++)
        A2[n] = -__expf(A_log[(size_t)d * D_STATE + n]) * LOG2E;

    float h[D_STATE], P[D_STATE];
    #pragma unroll
    for (int n = 0; n < D_STATE; n++) { h[n] = 0.f; P[n] = 1.f; }

    __shared__ float bs[CLEN][D_STATE];
    #pragma unroll
    for (int i = 0; i < 2; i++) {
        int lin = threadIdx.x + i * 256;
        int li = lin >> 4, j = lin & 15;
        bs[li][j] = dbl[(size_t)(b * LSEQ + c * CLEN + li) * 96 + 64 + j];
    }
    __syncthreads();

    int t0 = b * LSEQ + c * CLEN;
    for (int li = 0; li < CLEN; li++) {
        float dtv = dt[(size_t)(t0 + li) * D_INNER + d];
        float uv  = u[(size_t)(t0 + li) * D_INNER + d];
        float dbu = dtv * uv;
        #pragma unroll
        for (int n = 0; n < D_STATE; n++) {
            float dA = exp2f(dtv * A2[n]);
            h[n] = fmaf(dA, h[n], dbu * bs[li][n]);
            P[n] *= dA;
        }
    }
    size_t o = ((size_t)(b * NCHUNK + c) * D_INNER + d) * D_STATE;
    #pragma unroll
    for (int n = 0; n < D_STATE; n += 4) {
        float4 hv = make_float4(h[n], h[n+1], h[n+2], h[n+3]);
        float4 pv = make_float4(P[n], P[n+1], P[n+2], P[n+3]);
        *(float4*)&hloc[o + n] = hv;
        *(float4*)&Pc[o + n]   = pv;
    }
}

__global__ __launch_bounds__(256) void scan_combine_k(const float* __restrict__ hloc,
                                                      const float* __restrict__ Pc,
                                                      float* __restrict__ hin) {
    int gi = blockIdx.x * 256 + threadIdx.x;     // over B*D_INNER*D_STATE = 65536
    int n = gi & 15;
    int d = (gi >> 4) & (D_INNER - 1);
    int b = gi >> 15;
    float h = 0.f;
    #pragma unroll
    for (int c = 0; c < NCHUNK; c++) {
        size_t o = ((size_t)(b * NCHUNK + c) * D_INNER + d) * D_STATE + n;
        hin[o] = h;
        h = fmaf(Pc[o], h, hloc[o]);
    }
}

__global__ __launch_bounds__(256) void scan_pass2_k(const float* __restrict__ u,
                                                    const float* __restrict__ dt,
                                                    const float* __restrict__ dbl,
                                                    const float* __restrict__ A_log,
                                                    const float* __restrict__ Dp,
                                                    const float* __restrict__ hin,
                                                    float* __restrict__ y) {
    int d = blockIdx.x * 256 + threadIdx.x;
    int c = blockIdx.y;
    int b = blockIdx.z;
    float A2[D_STATE];
    #pragma unroll
    for (int n = 0; n < D_STATE; n++)
        A2[n] = -__expf(A_log[(size_t)d * D_STATE + n]) * LOG2E;
    float Dd = Dp[d];

    float h[D_STATE];
    {
        size_t o = ((size_t)(b * NCHUNK + c) * D_INNER + d) * D_STATE;
        #pragma unroll
        for (int n = 0; n < D_STATE; n += 4) {
            float4 hv = *(const float4*)&hin[o + n];
            h[n] = hv.x; h[n+1] = hv.y; h[n+2] = hv.z; h[n+3] = hv.w;
        }
    }

    __shared__ float bc[CLEN][32];
    #pragma unroll
    for (int i = 0; i < 4; i++) {
        int lin = threadIdx.x + i * 256;
        int li = lin >> 5, j = lin & 31;
        bc[li][j] = dbl[(size_t)(b * LSEQ + c * CLEN + li) * 96 + 64 + j];
    }
    __syncthreads();

    int t0 = b * LSEQ + c * CLEN;
    for (int li = 0; li < CLEN; li++) {
        int t = t0 + li;
        float dtv = dt[(size_t)t * D_INNER + d];
        float uv  = u[(size_t)t * D_INNER + d];
        float dbu = dtv * uv;
        float yv = 0.f;
        #pragma unroll
        for (int n = 0; n < D_STATE; n++) {
            float dA = exp2f(dtv * A2[n]);
            h[n] = fmaf(dA, h[n], dbu * bc[li][n]);
            yv = fmaf(h[n], bc[li][16 + n], yv);
        }
        y[(size_t)t * D_INNER + d] = yv + uv * Dd;
    }
}

// ---------------------------------------------------------------- gate -> bf16: yg = y * silu(z)
__global__ __launch_bounds__(256) void gate_bf_k(const float* __restrict__ xz,
                                                 const float* __restrict__ y,
                                                 __bf16* __restrict__ yg) {
    size_t base = ((size_t)blockIdx.x * 256 + threadIdx.x) * 4;  // over NTOK*D_INNER
    size_t t = base >> 11;
    int d = (int)(base & (D_INNER - 1));
    float4 yv = *(const float4*)&y[base];
    float4 zv = *(const float4*)&xz[t * (2 * D_INNER) + D_INNER + d];
    bf16x4 o;
    o[0] = (__bf16)(yv.x * zv.x / (1.f + __expf(-zv.x)));
    o[1] = (__bf16)(yv.y * zv.y / (1.f + __expf(-zv.y)));
    o[2] = (__bf16)(yv.z * zv.z / (1.f + __expf(-zv.z)));
    o[3] = (__bf16)(yv.w * zv.w / (1.f + __expf(-zv.w)));
    *(bf16x4*)&yg[base] = o;
}

// ---------------------------------------------------------------- launch
extern "C" void kernel_launch(void* const* d_in, const int* in_sizes, int n_in,
                              void* d_out, int out_size, void* d_ws, size_t ws_size,
                              hipStream_t stream) {
    const int*   tokens   = (const int*)  d_in[0];
    const float* emb      = (const float*)d_in[1];
    const float* norm_w   = (const float*)d_in[2];
    const float* in_proj  = (const float*)d_in[3];
    const float* conv_w   = (const float*)d_in[4];
    const float* conv_b   = (const float*)d_in[5];
    const float* x_proj   = (const float*)d_in[6];
    const float* dt_w     = (const float*)d_in[7];
    const float* dt_b     = (const float*)d_in[8];
    const float* A_log    = (const float*)d_in[9];
    const float* Dp       = (const float*)d_in[10];
    const float* out_proj = (const float*)d_in[11];
    const float* fin_w    = (const float*)d_in[12];
    const float* head_w   = (const float*)d_in[13];
    float* out = (float*)d_out;

    // d_ws layout (13.4 MB used; previous version used 17.6 MB — safe)
    float*  ws    = (float*)d_ws;
    float*  x     = ws;                          // 2,097,152 f
    __bf16* xn_bf = (__bf16*)(ws + 2097152);     // 2,097,152 bf16 = 1,048,576 f
    float*  dbl   = ws + 3145728;                //   196,608 f

    // d_out transient scratch (all consumed before the head GEMM overwrites out)
    // out region = 2048*32000 = 65,536,000 floats
    float*  xz    = out;                         // [0,        8388608)
    float*  u     = out + 8388608;               // [8388608, 12582912)
    float*  dt    = out + 12582912;              // [...,     16777216)
    float*  y     = out + 16777216;              // [...,     20971520)
    float*  hloc  = out + 20971520;              // [...,     23068672)
    float*  Pc    = out + 23068672;              // [...,     25165824)
    float*  hin   = out + 25165824;              // [...,     27262976)
    __bf16* inWt  = (__bf16*)(out + 27262976);   // 4*4096*1024 bf16 = 8,388,608 f
    __bf16* outWt = (__bf16*)(out + 35651584);   // 4*1024*2048 bf16 = 4,194,304 f
    __bf16* yg    = (__bf16*)(out + 39845888);   // 2048*2048 bf16   = 2,097,152 f  (ends 41,943,040)

    // one-time weight transpose+convert: Wt[n][k] = bf16(W[k][n])
    wconv_k<<<dim3(64, 16, N_LAYER), 256, 0, stream>>>(in_proj,  inWt,  D_MODEL, 2 * D_INNER);
    wconv_k<<<dim3(16, 32, N_LAYER), 256, 0, stream>>>(out_proj, outWt, D_INNER, D_MODEL);

    embed_k<<<NTOK, 256, 0, stream>>>(tokens, emb, x);

    for (int i = 0; i < N_LAYER; i++) {
        rmsnorm_bf_k<<<NTOK, 256, 0, stream>>>(x, norm_w + (size_t)i * D_MODEL, xn_bf);
        gemm_bfw_k<0><<<dim3(2 * D_INNER / 128, NTOK / 128), 256, 0, stream>>>(
            xn_bf, inWt + (size_t)i * 2 * D_INNER * D_MODEL, xz,
            NTOK, 2 * D_INNER, D_MODEL, nullptr);
        conv_silu_k<<<dim3(8, NTOK), 256, 0, stream>>>(
            xz, conv_w + (size_t)i * D_INNER * D_CONV, conv_b + (size_t)i * D_INNER, u);
        gemm_k<0><<<dim3(2, 32), 256, 0, stream>>>(
            u, x_proj + (size_t)i * D_INNER * 96, dbl,
            NTOK, 96, D_INNER, D_INNER, nullptr);
        gemm_k<1><<<dim3(32, 32), 256, 0, stream>>>(
            dbl, dt_w + (size_t)i * DT_RANK * D_INNER, dt,
            NTOK, D_INNER, DT_RANK, 96, dt_b + (size_t)i * D_INNER);

        scan_pass1_k<<<dim3(8, NCHUNK, BSZ), 256, 0, stream>>>(
            u, dt, dbl, A_log + (size_t)i * D_INNER * D_STATE, hloc, Pc);
        scan_combine_k<<<256, 256, 0, stream>>>(hloc, Pc, hin);
        scan_pass2_k<<<dim3(8, NCHUNK, BSZ), 256, 0, stream>>>(
            u, dt, dbl, A_log + (size_t)i * D_INNER * D_STATE,
            Dp + (size_t)i * D_INNER, hin, y);

        gate_bf_k<<<(NTOK * D_INNER) / 1024, 256, 0, stream>>>(xz, y, yg);
        gemm_bfw_k<2><<<dim3(D_MODEL / 128, NTOK / 128), 256, 0, stream>>>(
            yg, outWt + (size_t)i * D_MODEL * D_INNER, x,
            NTOK, D_MODEL, D_INNER, x);
    }

    rmsnorm_bf_k<<<NTOK, 256, 0, stream>>>(x, fin_w, xn_bf);
    // head GEMM: 2048 x 32000 x 1024 — A bf16 (ws, no alias), B fp32 on-the-fly,
    // M-block-fastest grid for B-panel L2/L3 reuse
    gemm_head_k<<<dim3(NTOK / 128, VOCAB / 128), 256, 0, stream>>>(
        xn_bf, head_w, out, NTOK, VOCAB, D_MODEL);
}

// Round 4
// 1582.344 us; speedup vs baseline: 5.1274x; 1.4799x over previous
//
#include <hip/hip_runtime.h>
#include <math.h>

#define D_MODEL 1024
#define D_INNER 2048
#define D_STATE 16
#define DT_RANK 64
#define D_CONV  4
#define N_LAYER 4
#define VOCAB   32000
#define EPS     1e-5f
#define BSZ     2
#define LSEQ    1024
#define NTOK    (BSZ*LSEQ)      // 2048 token rows

#define LOG2E   1.4426950408889634f

// chunked selective-scan decomposition
#define NCHUNK  32
#define CLEN    (LSEQ / NCHUNK)   // 32
#define KSPLIT  8                 // x_proj split-K factor

typedef __bf16 bf16x8 __attribute__((ext_vector_type(8)));
typedef __bf16 bf16x4 __attribute__((ext_vector_type(4)));
typedef float  f32x4  __attribute__((ext_vector_type(4)));

// async global->LDS, 16B per lane; LDS dest is wave-uniform base + lane*16
__device__ __forceinline__ void gload16(const void* g, void* l) {
    __builtin_amdgcn_global_load_lds(
        (const __attribute__((address_space(1))) void*)g,
        (__attribute__((address_space(3))) void*)l, 16, 0, 0);
}

// ---------------------------------------------------------------- embedding
__global__ void embed_k(const int* __restrict__ tokens,
                        const float* __restrict__ emb,
                        float* __restrict__ x) {
    int row = blockIdx.x;                       // 0..2047
    int t = tokens[row];
    const float4* src = (const float4*)(emb + (size_t)t * D_MODEL);
    float4* dst = (float4*)(x + (size_t)row * D_MODEL);
    dst[threadIdx.x] = src[threadIdx.x];        // 256 thr * 4 = 1024
}

// ---------------------------------------------------------------- rmsnorm -> bf16
__global__ __launch_bounds__(256) void rmsnorm_bf_k(const float* __restrict__ x,
                                                    const float* __restrict__ w,
                                                    __bf16* __restrict__ o) {
    int row = blockIdx.x;
    const float4* xr = (const float4*)(x + (size_t)row * D_MODEL);
    float4 v = xr[threadIdx.x];
    float ss = v.x*v.x + v.y*v.y + v.z*v.z + v.w*v.w;
    #pragma unroll
    for (int off = 32; off > 0; off >>= 1) ss += __shfl_down(ss, off, 64);
    __shared__ float sred[4];
    int wid = threadIdx.x >> 6, lane = threadIdx.x & 63;
    if (lane == 0) sred[wid] = ss;
    __syncthreads();
    float tot = sred[0] + sred[1] + sred[2] + sred[3];
    float scale = rsqrtf(tot * (1.0f / D_MODEL) + EPS);
    float4 wv = ((const float4*)w)[threadIdx.x];
    bf16x4 ov;
    ov[0] = (__bf16)(v.x * scale * wv.x);
    ov[1] = (__bf16)(v.y * scale * wv.y);
    ov[2] = (__bf16)(v.z * scale * wv.z);
    ov[3] = (__bf16)(v.w * scale * wv.w);
    *(bf16x4*)(o + (size_t)row * D_MODEL + threadIdx.x * 4) = ov;
}

// ---------------------------------------------------------------- fp32 GEMM (dt_proj)
// MODE 1: +bias[col], softplus
template<int MODE>
__global__ __launch_bounds__(256) void gemm_k(const float* __restrict__ A,
                                              const float* __restrict__ B,
                                              float* __restrict__ C,
                                              int M, int N, int K, int lda,
                                              const float* __restrict__ aux) {
    __shared__ float As[16][68];
    __shared__ float Bs[16][68];
    int tid = threadIdx.x;
    int tx = tid & 15, ty = tid >> 4;
    int rowBase = blockIdx.y * 64;
    int colBase = blockIdx.x * 64;
    float acc[4][4] = {};

    for (int k0 = 0; k0 < K; k0 += 16) {
        #pragma unroll
        for (int i = 0; i < 4; i++) {           // A tile: 64 rows x 16 k
            int lin = tid + i * 256;
            int r = lin >> 4, kk = lin & 15;
            As[kk][r] = A[(size_t)(rowBase + r) * lda + k0 + kk];
        }
        #pragma unroll
        for (int i = 0; i < 4; i++) {           // B tile: 16 k x 64 cols
            int lin = tid + i * 256;
            int kk = lin >> 6, c = lin & 63;
            int col = colBase + c;
            Bs[kk][c] = (col < N) ? B[(size_t)(k0 + kk) * N + col] : 0.f;
        }
        __syncthreads();
        #pragma unroll
        for (int kk = 0; kk < 16; kk++) {
            float4 a4 = *(const float4*)&As[kk][ty * 4];
            float4 b4 = *(const float4*)&Bs[kk][tx * 4];
            float av[4] = {a4.x, a4.y, a4.z, a4.w};
            float bv[4] = {b4.x, b4.y, b4.z, b4.w};
            #pragma unroll
            for (int i = 0; i < 4; i++)
                #pragma unroll
                for (int j = 0; j < 4; j++)
                    acc[i][j] = fmaf(av[i], bv[j], acc[i][j]);
        }
        __syncthreads();
    }

    int col = colBase + tx * 4;
    if (col < N) {
        #pragma unroll
        for (int i = 0; i < 4; i++) {
            int row = rowBase + ty * 4 + i;
            float v0 = acc[i][0], v1 = acc[i][1], v2 = acc[i][2], v3 = acc[i][3];
            if (MODE == 1) {
                const float4 bb = *(const float4*)&aux[col];
                v0 += bb.x; v1 += bb.y; v2 += bb.z; v3 += bb.w;
                v0 = (v0 > 20.f) ? v0 : log1pf(__expf(v0));
                v1 = (v1 > 20.f) ? v1 : log1pf(__expf(v1));
                v2 = (v2 > 20.f) ? v2 : log1pf(__expf(v2));
                v3 = (v3 > 20.f) ? v3 : log1pf(__expf(v3));
            }
            float4 ov; ov.x = v0; ov.y = v1; ov.z = v2; ov.w = v3;
            *(float4*)&C[(size_t)row * N + col] = ov;
        }
    }
}

// ---------------------------------------------------------------- fp32 split-K GEMM (x_proj)
// Partial C over K-chunk blockIdx.z; Cp[s][M][N].
__global__ __launch_bounds__(256) void gemm_splitk_k(const float* __restrict__ A,
                                                     const float* __restrict__ B,
                                                     float* __restrict__ Cp,
                                                     int M, int N, int K, int lda) {
    __shared__ float As[16][68];
    __shared__ float Bs[16][68];
    int tid = threadIdx.x;
    int tx = tid & 15, ty = tid >> 4;
    int rowBase = blockIdx.y * 64;
    int colBase = blockIdx.x * 64;
    int kchunk = K / KSPLIT;
    int kbeg = blockIdx.z * kchunk, kend = kbeg + kchunk;
    float acc[4][4] = {};

    for (int k0 = kbeg; k0 < kend; k0 += 16) {
        #pragma unroll
        for (int i = 0; i < 4; i++) {
            int lin = tid + i * 256;
            int r = lin >> 4, kk = lin & 15;
            As[kk][r] = A[(size_t)(rowBase + r) * lda + k0 + kk];
        }
        #pragma unroll
        for (int i = 0; i < 4; i++) {
            int lin = tid + i * 256;
            int kk = lin >> 6, c = lin & 63;
            int col = colBase + c;
            Bs[kk][c] = (col < N) ? B[(size_t)(k0 + kk) * N + col] : 0.f;
        }
        __syncthreads();
        #pragma unroll
        for (int kk = 0; kk < 16; kk++) {
            float4 a4 = *(const float4*)&As[kk][ty * 4];
            float4 b4 = *(const float4*)&Bs[kk][tx * 4];
            float av[4] = {a4.x, a4.y, a4.z, a4.w};
            float bv[4] = {b4.x, b4.y, b4.z, b4.w};
            #pragma unroll
            for (int i = 0; i < 4; i++)
                #pragma unroll
                for (int j = 0; j < 4; j++)
                    acc[i][j] = fmaf(av[i], bv[j], acc[i][j]);
        }
        __syncthreads();
    }

    float* Cs = Cp + (size_t)blockIdx.z * M * N;
    int col = colBase + tx * 4;
    if (col < N) {
        #pragma unroll
        for (int i = 0; i < 4; i++) {
            int row = rowBase + ty * 4 + i;
            float4 ov; ov.x = acc[i][0]; ov.y = acc[i][1]; ov.z = acc[i][2]; ov.w = acc[i][3];
            *(float4*)&Cs[(size_t)row * N + col] = ov;
        }
    }
}

// reduce KSPLIT partials: C[i] = sum_s Cp[s][i]   (float4 per thread)
__global__ __launch_bounds__(256) void reduce_splitk_k(const float* __restrict__ Cp,
                                                       float* __restrict__ C,
                                                       int total4) {
    int i = blockIdx.x * 256 + threadIdx.x;       // float4 index
    if (i >= total4) return;
    f32x4 acc = {};
    #pragma unroll
    for (int s = 0; s < KSPLIT; s++)
        acc += *(const f32x4*)(Cp + ((size_t)s * total4 + i) * 4);
    *(f32x4*)(C + (size_t)i * 4) = acc;
}

// ---------------------------------------------------------------- weight transpose+convert
// Wt[n][k] = (bf16) W[k][n]   per layer (blockIdx.z)
__global__ __launch_bounds__(256) void wconv_k(const float* __restrict__ W,
                                               __bf16* __restrict__ Wt,
                                               int K, int N) {
    W  += (size_t)blockIdx.z * K * N;
    Wt += (size_t)blockIdx.z * N * K;
    __shared__ float t[64][65];
    int n0 = blockIdx.x * 64, k0 = blockIdx.y * 64;
    #pragma unroll
    for (int i = 0; i < 16; i++) {
        int lin = threadIdx.x + i * 256;
        int r = lin >> 6, c = lin & 63;         // r = k-local, c = n-local
        t[r][c] = W[(size_t)(k0 + r) * N + n0 + c];
    }
    __syncthreads();
    #pragma unroll
    for (int i = 0; i < 16; i++) {
        int lin = threadIdx.x + i * 256;
        int nr = lin >> 6, kc = lin & 63;
        Wt[(size_t)(n0 + nr) * K + k0 + kc] = (__bf16)t[kc][nr];
    }
}

// ---------------------------------------------------------------- bf16 MFMA GEMM, pre-converted inputs
// C[M,N] = A[M,K] @ Bt[N,K]^T ; A,Bt bf16 (k-contiguous), C fp32.
// MODE 0: plain   MODE 2: + aux[row,col] residual
// 128x128 tile, BK=64, 4 waves 2x2, global_load_lds(16B) staging.
// LDS layout: [row][64] bf16, XOR-swizzled via PRE-SWIZZLED GLOBAL SOURCE
// (rule 21: gload_lds writes linearly, so source col = ((lane&7)^(lane>>3))*8)
// + matching XOR on read: elem_off = m*64 + (kb ^ ((m&7)<<3)).
// Was a 16-way bank conflict (all rows start at same bank with 128B stride).
template<int MODE>
__global__ __launch_bounds__(256) void gemm_bfw_k(const __bf16* __restrict__ A,
                                                  const __bf16* __restrict__ Bt,
                                                  float* __restrict__ C,
                                                  int M, int N, int K,
                                                  const float* __restrict__ aux) {
    __shared__ __align__(16) __bf16 sA[128 * 64];
    __shared__ __align__(16) __bf16 sB[128 * 64];
    int tid  = threadIdx.x;
    int lane = tid & 63;
    int w    = tid >> 6;
    int wr   = w >> 1, wc = w & 1;
    int rowBase = blockIdx.y * 128;
    int n0      = blockIdx.x * 128;

    // staging: wave w covers rows [w*32, w*32+32); slot i adds 8 rows.
    // row&7 == lane>>3 for every slot, so the swizzled source col is lane-only.
    int srow = w * 32 + (lane >> 3);
    int scol = ((lane & 7) ^ (lane >> 3)) << 3;    // pre-swizzled k-offset (elements)
    const __bf16* Ag = A  + (size_t)(rowBase + srow) * K + scol;
    const __bf16* Bg = Bt + (size_t)(n0      + srow) * K + scol;

    f32x4 acc[4][4] = {};

    for (int k0 = 0; k0 < K; k0 += 64) {
        #pragma unroll
        for (int i = 0; i < 4; i++) {
            gload16(Ag + (size_t)i * 8 * K + k0, sA + (w * 4 + i) * 512);
            gload16(Bg + (size_t)i * 8 * K + k0, sB + (w * 4 + i) * 512);
        }
        __syncthreads();                        // vmcnt(0) drain + all waves staged

        #pragma unroll
        for (int ks = 0; ks < 2; ks++) {
            int kb = ks * 32 + (lane >> 4) * 8; // k-elem offset of this lane's 8 k's
            bf16x8 af[4], bfr[4];
            #pragma unroll
            for (int mi = 0; mi < 4; mi++) {
                int m = wr * 64 + mi * 16 + (lane & 15);
                af[mi] = *(const bf16x8*)(sA + m * 64 + (kb ^ ((m & 7) << 3)));
            }
            #pragma unroll
            for (int ni = 0; ni < 4; ni++) {
                int n = wc * 64 + ni * 16 + (lane & 15);
                bfr[ni] = *(const bf16x8*)(sB + n * 64 + (kb ^ ((n & 7) << 3)));
            }
            #pragma unroll
            for (int mi = 0; mi < 4; mi++)
                #pragma unroll
                for (int ni = 0; ni < 4; ni++)
                    acc[mi][ni] = __builtin_amdgcn_mfma_f32_16x16x32_bf16(
                        af[mi], bfr[ni], acc[mi][ni], 0, 0, 0);
        }
        __syncthreads();                        // LDS consumed; safe to restage
    }

    // epilogue: C/D layout col=lane&15, row=(lane>>4)*4+reg
    #pragma unroll
    for (int mi = 0; mi < 4; mi++) {
        int row = rowBase + wr * 64 + mi * 16 + (lane >> 4) * 4;
        #pragma unroll
        for (int ni = 0; ni < 4; ni++) {
            int col = n0 + wc * 64 + ni * 16 + (lane & 15);
            #pragma unroll
            for (int r = 0; r < 4; r++) {
                float v = acc[mi][ni][r];
                if (MODE == 2) v += aux[(size_t)(row + r) * N + col];
                C[(size_t)(row + r) * N + col] = v;
            }
        }
    }
}

// ---------------------------------------------------------------- head GEMM
// A bf16 [M][K]; B fp32 [K][N] converted on the fly; C fp32.
// 1D grid 4000 with XCD-chunked remap: all 16 M-blocks of a 128-col B panel
// land on ONE XCD (bid%8), consecutive panels per XCD -> B fetched ~once.
__global__ __launch_bounds__(256) void gemm_head_k(const __bf16* __restrict__ A,
                                                   const float* __restrict__ B,
                                                   float* __restrict__ C,
                                                   int M, int N, int K) {
    __shared__ __align__(16) char sA[128 * 128];
    __shared__ __align__(16) char sB[128 * 128];
    int tid  = threadIdx.x;
    int lane = tid & 63;
    int w    = tid >> 6;
    int wr   = w >> 1, wc = w & 1;

    // XCD-chunked bijective remap (nwg=4000, 4000%8==0)
    int bid  = blockIdx.x;
    int nper = gridDim.x >> 3;                     // 500
    int lin  = (bid & 7) * nper + (bid >> 3);
    int rowBase = (lin & 15) * 128;                // m-block fastest within panel
    int n0      = (lin >> 4) * 128;

    int ar  = tid >> 1;                            // A: row 0..127
    int akh = (tid & 1) * 32;                      // A: k-half (elements)
    int bn  = tid & 127;                           // B: col 0..127
    int bkh = (tid >> 7) * 32;                     // B: k-half

    f32x4 acc[4][4] = {};

    const __bf16* Abase = A + (size_t)(rowBase + ar) * K + akh;
    const float*  Bbase = B + (size_t)bkh * N + n0 + bn;

    for (int k0 = 0; k0 < K; k0 += 64) {
        bf16x8 a8[4];                              // 32 bf16 of one A row-half
        #pragma unroll
        for (int i = 0; i < 4; i++)
            a8[i] = *(const bf16x8*)(Abase + k0 + i * 8);
        float bval[32];                            // 32 k's of one B column
        #pragma unroll
        for (int j = 0; j < 32; j++)
            bval[j] = Bbase[(size_t)(k0 + j) * N];

        __syncthreads();                           // previous tile's LDS reads done

        #pragma unroll
        for (int i = 0; i < 4; i++) {
            int off = (ar * 128 + akh * 2 + i * 16) ^ ((ar & 7) << 4);
            *(bf16x8*)(sA + off) = a8[i];
        }
        #pragma unroll
        for (int j = 0; j < 4; j++) {              // B^T: 32 floats -> 4x bf16x8
            bf16x8 p;
            #pragma unroll
            for (int e = 0; e < 8; e++) p[e] = (__bf16)bval[8 * j + e];
            int off = (bn * 128 + bkh * 2 + j * 16) ^ ((bn & 7) << 4);
            *(bf16x8*)(sB + off) = p;
        }
        __syncthreads();

        #pragma unroll
        for (int ks = 0; ks < 2; ks++) {
            int kb = ks * 64 + (lane >> 4) * 16;   // byte offset of this lane's 8 k's
            bf16x8 af[4], bfr[4];
            #pragma unroll
            for (int mi = 0; mi < 4; mi++) {
                int m = wr * 64 + mi * 16 + (lane & 15);
                af[mi] = *(const bf16x8*)(sA + ((m * 128 + kb) ^ ((m & 7) << 4)));
            }
            #pragma unroll
            for (int ni = 0; ni < 4; ni++) {
                int n = wc * 64 + ni * 16 + (lane & 15);
                bfr[ni] = *(const bf16x8*)(sB + ((n * 128 + kb) ^ ((n & 7) << 4)));
            }
            #pragma unroll
            for (int mi = 0; mi < 4; mi++)
                #pragma unroll
                for (int ni = 0; ni < 4; ni++)
                    acc[mi][ni] = __builtin_amdgcn_mfma_f32_16x16x32_bf16(
                        af[mi], bfr[ni], acc[mi][ni], 0, 0, 0);
        }
    }

    #pragma unroll
    for (int mi = 0; mi < 4; mi++) {
        int row = rowBase + wr * 64 + mi * 16 + (lane >> 4) * 4;
        #pragma unroll
        for (int ni = 0; ni < 4; ni++) {
            int col = n0 + wc * 64 + ni * 16 + (lane & 15);
            #pragma unroll
            for (int r = 0; r < 4; r++)
                C[(size_t)(row + r) * N + col] = acc[mi][ni][r];
        }
    }
}

// ---------------------------------------------------------------- conv1d + silu
__global__ __launch_bounds__(256) void conv_silu_k(const float* __restrict__ xz,
                                                   const float* __restrict__ cw,
                                                   const float* __restrict__ cb,
                                                   float* __restrict__ u) {
    int d = blockIdx.x * 256 + threadIdx.x;     // 0..2047
    int t = blockIdx.y;                          // b*L + l
    int l = t & (LSEQ - 1);
    float acc = cb[d];
    #pragma unroll
    for (int k = 0; k < D_CONV; k++) {
        int ll = l - (D_CONV - 1) + k;
        if (ll >= 0)
            acc = fmaf(cw[d * D_CONV + k], xz[(size_t)(t - (D_CONV - 1) + k) * (2 * D_INNER) + d], acc);
    }
    float s = acc / (1.f + __expf(-acc));        // silu
    u[(size_t)t * D_INNER + d] = s;
}

// ---------------------------------------------------------------- chunked selective scan
__global__ __launch_bounds__(256) void scan_pass1_k(const float* __restrict__ u,
                                                    const float* __restrict__ dt,
                                                    const float* __restrict__ dbl,
                                                    const float* __restrict__ A_log,
                                                    float* __restrict__ hloc,
                                                    float* __restrict__ Pc) {
    int d = blockIdx.x * 256 + threadIdx.x;      // 0..2047
    int c = blockIdx.y;                          // chunk
    int b = blockIdx.z;
    float A2[D_STATE];
    #pragma unroll
    for (int n = 0; n < D_STATE; n++)
        A2[n] = -__expf(A_log[(size_t)d * D_STATE + n]) * LOG2E;

    float h[D_STATE], P[D_STATE];
    #pragma unroll
    for (int n = 0; n < D_STATE; n++) { h[n] = 0.f; P[n] = 1.f; }

    __shared__ float bs[CLEN][D_STATE];
    #pragma unroll
    for (int i = 0; i < 2; i++) {
        int lin = threadIdx.x + i * 256;
        int li = lin >> 4, j = lin & 15;
        bs[li][j] = dbl[(size_t)(b * LSEQ + c * CLEN + li) * 96 + 64 + j];
    }
    __syncthreads();

    int t0 = b * LSEQ + c * CLEN;
    for (int li = 0; li < CLEN; li++) {
        float dtv = dt[(size_t)(t0 + li) * D_INNER + d];
        float uv  = u[(size_t)(t0 + li) * D_INNER + d];
        float dbu = dtv * uv;
        #pragma unroll
        for (int n = 0; n < D_STATE; n++) {
            float dA = exp2f(dtv * A2[n]);
            h[n] = fmaf(dA, h[n], dbu * bs[li][n]);
            P[n] *= dA;
        }
    }
    size_t o = ((size_t)(b * NCHUNK + c) * D_INNER + d) * D_STATE;
    #pragma unroll
    for (int n = 0; n < D_STATE; n += 4) {
        float4 hv = make_float4(h[n], h[n+1], h[n+2], h[n+3]);
        float4 pv = make_float4(P[n], P[n+1], P[n+2], P[n+3]);
        *(float4*)&hloc[o + n] = hv;
        *(float4*)&Pc[o + n]   = pv;
    }
}

__global__ __launch_bounds__(256) void scan_combine_k(const float* __restrict__ hloc,
                                                      const float* __restrict__ Pc,
                                                      float* __restrict__ hin) {
    int gi = blockIdx.x * 256 + threadIdx.x;     // over B*D_INNER*D_STATE = 65536
    int n = gi & 15;
    int d = (gi >> 4) & (D_INNER - 1);
    int b = gi >> 15;
    float h = 0.f;
    #pragma unroll
    for (int c = 0; c < NCHUNK; c++) {
        size_t o = ((size_t)(b * NCHUNK + c) * D_INNER + d) * D_STATE + n;
        hin[o] = h;
        h = fmaf(Pc[o], h, hloc[o]);
    }
}

// pass2 with FUSED GATE: yg = bf16( (scan_y + u*D) * silu(z) )
__global__ __launch_bounds__(256) void scan_pass2_k(const float* __restrict__ u,
                                                    const float* __restrict__ dt,
                                                    const float* __restrict__ dbl,
                                                    const float* __restrict__ A_log,
                                                    const float* __restrict__ Dp,
                                                    const float* __restrict__ hin,
                                                    const float* __restrict__ xz,
                                                    __bf16* __restrict__ yg) {
    int d = blockIdx.x * 256 + threadIdx.x;
    int c = blockIdx.y;
    int b = blockIdx.z;
    float A2[D_STATE];
    #pragma unroll
    for (int n = 0; n < D_STATE; n++)
        A2[n] = -__expf(A_log[(size_t)d * D_STATE + n]) * LOG2E;
    float Dd = Dp[d];

    float h[D_STATE];
    {
        size_t o = ((size_t)(b * NCHUNK + c) * D_INNER + d) * D_STATE;
        #pragma unroll
        for (int n = 0; n < D_STATE; n += 4) {
            float4 hv = *(const float4*)&hin[o + n];
            h[n] = hv.x; h[n+1] = hv.y; h[n+2] = hv.z; h[n+3] = hv.w;
        }
    }

    __shared__ float bc[CLEN][32];
    #pragma unroll
    for (int i = 0; i < 4; i++) {
        int lin = threadIdx.x + i * 256;
        int li = lin >> 5, j = lin & 31;
        bc[li][j] = dbl[(size_t)(b * LSEQ + c * CLEN + li) * 96 + 64 + j];
    }
    __syncthreads();

    int t0 = b * LSEQ + c * CLEN;
    for (int li = 0; li < CLEN; li++) {
        int t = t0 + li;
        float dtv = dt[(size_t)t * D_INNER + d];
        float uv  = u[(size_t)t * D_INNER + d];
        float dbu = dtv * uv;
        float yv = 0.f;
        #pragma unroll
        for (int n = 0; n < D_STATE; n++) {
            float dA = exp2f(dtv * A2[n]);
            h[n] = fmaf(dA, h[n], dbu * bc[li][n]);
            yv = fmaf(h[n], bc[li][16 + n], yv);
        }
        float z = xz[(size_t)t * (2 * D_INNER) + D_INNER + d];
        float g = z / (1.f + __expf(-z));
        yg[(size_t)t * D_INNER + d] = (__bf16)((yv + uv * Dd) * g);
    }
}

// ---------------------------------------------------------------- launch
extern "C" void kernel_launch(void* const* d_in, const int* in_sizes, int n_in,
                              void* d_out, int out_size, void* d_ws, size_t ws_size,
                              hipStream_t stream) {
    const int*   tokens   = (const int*)  d_in[0];
    const float* emb      = (const float*)d_in[1];
    const float* norm_w   = (const float*)d_in[2];
    const float* in_proj  = (const float*)d_in[3];
    const float* conv_w   = (const float*)d_in[4];
    const float* conv_b   = (const float*)d_in[5];
    const float* x_proj   = (const float*)d_in[6];
    const float* dt_w     = (const float*)d_in[7];
    const float* dt_b     = (const float*)d_in[8];
    const float* A_log    = (const float*)d_in[9];
    const float* Dp       = (const float*)d_in[10];
    const float* out_proj = (const float*)d_in[11];
    const float* fin_w    = (const float*)d_in[12];
    const float* head_w   = (const float*)d_in[13];
    float* out = (float*)d_out;

    // d_ws layout (13.4 MB used)
    float*  ws    = (float*)d_ws;
    float*  x     = ws;                          // 2,097,152 f
    __bf16* xn_bf = (__bf16*)(ws + 2097152);     // 2,097,152 bf16 = 1,048,576 f
    float*  dbl   = ws + 3145728;                //   196,608 f

    // d_out transient scratch (all dead before the head GEMM writes out)
    float*  xz    = out;                         // [0,        8388608)
    float*  u     = out + 8388608;               // [8388608, 12582912)
    float*  dt    = out + 12582912;              // [...,     16777216)
    float*  xpart = out + 16777216;              // KSPLIT*2048*96 = 1,572,864 f (old y slot)
    float*  hloc  = out + 20971520;              // 2,097,152
    float*  Pc    = out + 23068672;              // 2,097,152
    float*  hin   = out + 25165824;              // 2,097,152
    __bf16* inWt  = (__bf16*)(out + 27262976);   // 4*4096*1024 bf16 = 8,388,608 f
    __bf16* outWt = (__bf16*)(out + 35651584);   // 4*1024*2048 bf16 = 4,194,304 f
    __bf16* yg    = (__bf16*)(out + 39845888);   // 2048*2048 bf16   = 2,097,152 f  (ends 41,943,040)

    // one-time weight transpose+convert: Wt[n][k] = bf16(W[k][n])
    wconv_k<<<dim3(64, 16, N_LAYER), 256, 0, stream>>>(in_proj,  inWt,  D_MODEL, 2 * D_INNER);
    wconv_k<<<dim3(16, 32, N_LAYER), 256, 0, stream>>>(out_proj, outWt, D_INNER, D_MODEL);

    embed_k<<<NTOK, 256, 0, stream>>>(tokens, emb, x);

    for (int i = 0; i < N_LAYER; i++) {
        rmsnorm_bf_k<<<NTOK, 256, 0, stream>>>(x, norm_w + (size_t)i * D_MODEL, xn_bf);
        gemm_bfw_k<0><<<dim3(2 * D_INNER / 128, NTOK / 128), 256, 0, stream>>>(
            xn_bf, inWt + (size_t)i * 2 * D_INNER * D_MODEL, xz,
            NTOK, 2 * D_INNER, D_MODEL, nullptr);
        conv_silu_k<<<dim3(8, NTOK), 256, 0, stream>>>(
            xz, conv_w + (size_t)i * D_INNER * D_CONV, conv_b + (size_t)i * D_INNER, u);

        // x_proj: split-K (was 64 blocks = 1 wave/SIMD, latency-bound)
        gemm_splitk_k<<<dim3(2, 32, KSPLIT), 256, 0, stream>>>(
            u, x_proj + (size_t)i * D_INNER * 96, xpart,
            NTOK, 96, D_INNER, D_INNER);
        reduce_splitk_k<<<(NTOK * 96 / 4 + 255) / 256, 256, 0, stream>>>(
            xpart, dbl, NTOK * 96 / 4);

        gemm_k<1><<<dim3(32, 32), 256, 0, stream>>>(
            dbl, dt_w + (size_t)i * DT_RANK * D_INNER, dt,
            NTOK, D_INNER, DT_RANK, 96, dt_b + (size_t)i * D_INNER);

        scan_pass1_k<<<dim3(8, NCHUNK, BSZ), 256, 0, stream>>>(
            u, dt, dbl, A_log + (size_t)i * D_INNER * D_STATE, hloc, Pc);
        scan_combine_k<<<256, 256, 0, stream>>>(hloc, Pc, hin);
        scan_pass2_k<<<dim3(8, NCHUNK, BSZ), 256, 0, stream>>>(
            u, dt, dbl, A_log + (size_t)i * D_INNER * D_STATE,
            Dp + (size_t)i * D_INNER, hin, xz, yg);

        gemm_bfw_k<2><<<dim3(D_MODEL / 128, NTOK / 128), 256, 0, stream>>>(
            yg, outWt + (size_t)i * D_MODEL * D_INNER, x,
            NTOK, D_MODEL, D_INNER, x);
    }

    rmsnorm_bf_k<<<NTOK, 256, 0, stream>>>(x, fin_w, xn_bf);
    // head GEMM: 2048 x 32000 x 1024 — 1D grid, XCD-chunked remap
    gemm_head_k<<<4000, 256, 0, stream>>>(xn_bf, head_w, out, NTOK, VOCAB, D_MODEL);
}